// Round 1
// baseline (104.496 us; speedup 1.0000x reference)
//
#include <hip/hip_runtime.h>

#define T_LEN 512
#define K_LEN 64
#define BIGV  1e9f
#define NFILT 32
#define NBATCH 64

// One wave (64 lanes) per (b,f) DP problem; lane j owns column j.
// Anti-diagonal sweep d = 0..T+K-2; at step d lane j computes cell (i=d-j, j).
//   up   = own prev value               (D[i-1, j])
//   left = shfl_up(prev, 1)             (D[i,   j-1])
//   dg   = last step's left             (D[i-1, j-1])  <- no 2nd shuffle needed
__global__ __launch_bounds__(256) void dtw_kernel(const float* __restrict__ x,
                                                  const float* __restrict__ protos,
                                                  float* __restrict__ out) {
    __shared__ float xs[T_LEN];
    const int tid  = threadIdx.x;
    const int lane = tid & 63;
    const int wid  = tid >> 6;
    const int b    = blockIdx.x >> 3;               // 8 blocks of f-groups per b
    const int f    = ((blockIdx.x & 7) << 2) | wid; // 4 waves/block, one f each

    // stage x[b, :] once per block (all 4 waves share b)
    for (int t = tid; t < T_LEN; t += 256) xs[t] = x[b * T_LEN + t];
    __syncthreads();

    const float p  = protos[f * K_LEN + lane];
    const float jj = (float)lane / 63.0f;

    // Exact fp32 band interval for this column, via binary search on the
    // reference predicate. Band membership: -0.2f <= i/511.f - jj <= 0.2f.
    // ii - jj is monotone nondecreasing in i, so each one-sided predicate is
    // a prefix/suffix -> the band is exactly the interval [ilo, ihi].
    int a0 = 0, b0 = T_LEN - 1;
    while (a0 < b0) {                       // first i with ii - jj >= -0.2f
        int m = (a0 + b0) >> 1;
        if ((float)m / 511.0f - jj >= -0.2f) b0 = m; else a0 = m + 1;
    }
    const int ilo = a0;
    a0 = 0; b0 = T_LEN - 1;
    while (a0 < b0) {                       // last i with ii - jj <= 0.2f
        int m = (a0 + b0 + 1) >> 1;
        if ((float)m / 511.0f - jj <= 0.2f) a0 = m; else b0 = m - 1;
    }
    const int ihi = a0;

    float prev = BIGV;   // D[i-1, j] (own cell on previous diagonal)
    float dgp  = BIGV;   // left from previous step == D[i-1, j-1]

#pragma unroll 5
    for (int d = 0; d < T_LEN + K_LEN - 1; ++d) {
        float left = __shfl_up(prev, 1);
        if (lane == 0) left = BIGV;                      // D[i, -1] = BIG
        float dg = (lane == 0) ? ((d == 0) ? 0.0f : BIGV) // D[-1,-1]=0 else BIG
                               : dgp;
        const int i = d - lane;
        float val = prev;                                // carry when inactive
        if (i >= 0 && i < T_LEN) {
            float diff = xs[i] - p;
            float c    = diff * diff;
            float up   = prev;
            // stable softmin3, GAMMA = 1 (identical form to jax logsumexp)
            float mn = fminf(fminf(up, left), dg);
            float s  = __expf(mn - up) + __expf(mn - left) + __expf(mn - dg);
            float sm = mn - __logf(s);
            val = c + sm;
            if (i < ilo || i > ihi) val = BIGV;          // outside band
        }
        dgp  = left;
        prev = val;
    }

    // lane 63 holds D[T-1, K-1] after the last diagonal
    if (lane == 63) out[b * NFILT + f] = prev * (1.0f / (float)T_LEN);
}

extern "C" void kernel_launch(void* const* d_in, const int* in_sizes, int n_in,
                              void* d_out, int out_size, void* d_ws, size_t ws_size,
                              hipStream_t stream) {
    const float* x      = (const float*)d_in[0];
    const float* protos = (const float*)d_in[1];
    float* out          = (float*)d_out;

    dim3 grid(NBATCH * (NFILT / 4));  // 512 blocks: 8 f-groups per batch row
    dim3 block(256);                  // 4 waves, one (b,f) problem each
    hipLaunchKernelGGL(dtw_kernel, grid, block, 0, stream, x, protos, out);
}

// Round 2
// 33.206 us; speedup vs baseline: 3.1469x; 3.1469x over previous
//
#include <hip/hip_runtime.h>

#define T_LEN  512
#define K_LEN  64
#define NFILT  32
#define NBATCH 64
#define XOFS   64                 // pad so xs index (XOFS + d - lane) >= 1 always
#define XS_SZ  (XOFS + 576)      // max read idx = XOFS + 574 = 638 < 640
#define NCHUNK 35
#define CHUNK  16
#define TAIL   15                 // 35*16 + 15 = 575 diagonals
#define SQRT_LOG2E 1.2011224087864498f
#define LN2        0.6931471805599453f

// left-neighbor shift: result[lane] = src[lane-1], lane0 -> 0 (bound_ctrl).
// 0x138 = DPP wave_shr:1 (gfx9/CDNA encoding).
static __device__ __forceinline__ float wave_shr1(float x) {
    int r = __builtin_amdgcn_update_dpp(0, __builtin_bit_cast(int, x),
                                        0x138, 0xF, 0xF, true);
    return __builtin_bit_cast(float, r);
}

// rotate within 16-lane row (0x120 + N = row_ror:N) — for the max-reduce
template <int N>
static __device__ __forceinline__ float row_ror(float x) {
    int r = __builtin_amdgcn_update_dpp(0, __builtin_bit_cast(int, x),
                                        0x120 + N, 0xF, 0xF, true);
    return __builtin_bit_cast(float, r);
}

static __device__ __forceinline__ float exp2_fast(float x) {
#if __has_builtin(__builtin_amdgcn_exp2f)
    return __builtin_amdgcn_exp2f(x);   // v_exp_f32
#else
    return exp2f(x);
#endif
}

// One wave per (b,f) problem; lane j = column j. Anti-diagonal sweep in the
// LINEAR domain: Z = 2^S2 * exp(-D). Recurrence:
//   Z[i,j] = exp(-C[i,j]) * (Z[i-1,j] + Z[i,j-1] + Z[i-1,j-1])
// BIG (out-of-band / border) == 0 exactly. Wave-uniform power-of-2 rescale
// every CHUNK steps keeps Z in fp32 range; S2 accumulates the shifts.
__global__ __launch_bounds__(256) void dtw_kernel(const float* __restrict__ x,
                                                  const float* __restrict__ protos,
                                                  float* __restrict__ out) {
    __shared__ float xs[XS_SZ];
    const int tid  = threadIdx.x;
    const int lane = tid & 63;
    const int wid  = tid >> 6;
    const int b    = blockIdx.x >> 3;
    const int f    = ((blockIdx.x & 7) << 2) | wid;

    // stage x[b,:] pre-scaled by sqrt(log2 e):  (diff*s)^2 = C * log2(e)
    for (int t = tid; t < XS_SZ; t += 256) {
        int i = t - XOFS;
        xs[t] = (i >= 0 && i < T_LEN) ? x[b * T_LEN + i] * SQRT_LOG2E : 0.0f;
    }
    __syncthreads();

    const float p  = protos[f * K_LEN + lane] * SQRT_LOG2E;
    const float jj = (float)lane / 63.0f;

    // exact fp32 band interval per column (same predicate as reference)
    int a0 = 0, b0 = T_LEN - 1;
    while (a0 < b0) { int m = (a0 + b0) >> 1;
        if ((float)m / 511.0f - jj >= -0.2f) b0 = m; else a0 = m + 1; }
    const int ilo = a0;
    a0 = 0; b0 = T_LEN - 1;
    while (a0 < b0) { int m = (a0 + b0 + 1) >> 1;
        if ((float)m / 511.0f - jj <= 0.2f) a0 = m; else b0 = m - 1; }
    const int ihi = a0;

    // active window in diagonal index d: [lane+ilo, lane+ihi]
    const unsigned range = (unsigned)(ihi - ilo);
    unsigned t = (unsigned)(-(lane + ilo));       // t = d - dlo at d = 0
    float prev = 0.0f;                            // Z on previous diagonal
    float dgp  = (lane == 0) ? 1.0f : 0.0f;       // Z[-1,-1] = e^0 = 1
    int   S2   = 0;
    int   xb   = XOFS - lane;                     // xs index at d = 0

    for (int c = 0; c < NCHUNK; ++c) {
#pragma unroll
        for (int k = 0; k < CHUNK; ++k) {
            float xv   = xs[xb + k];              // ds_read, imm offset
            float df   = xv - p;
            float w    = exp2_fast(-(df * df));   // e^{-C}, off critical chain
            w          = (t <= range) ? w : 0.0f; // band+valid mask -> exact 0
            float left = wave_shr1(prev);         // Z[i, j-1]; lane0 -> 0
            float sum  = (prev + left) + dgp;     // up + left + diag
            dgp  = left;                          // becomes diag next step
            prev = sum * w;
            ++t;
        }
        xb += CHUNK;

        // --- wave-uniform power-of-2 renormalization (target max ~ 2^30) ---
        float m = prev;
        m = fmaxf(m, row_ror<8>(m));
        m = fmaxf(m, row_ror<4>(m));
        m = fmaxf(m, row_ror<2>(m));
        m = fmaxf(m, row_ror<1>(m));              // per-16-row max in all lanes
        int mi = __builtin_bit_cast(int, m);
        unsigned m0 = (unsigned)__builtin_amdgcn_readlane(mi, 0);
        unsigned m1 = (unsigned)__builtin_amdgcn_readlane(mi, 16);
        unsigned m2 = (unsigned)__builtin_amdgcn_readlane(mi, 32);
        unsigned m3 = (unsigned)__builtin_amdgcn_readlane(mi, 48);
        unsigned ma = m0 > m1 ? m0 : m1;
        unsigned mb = m2 > m3 ? m2 : m3;
        unsigned mx = ma > mb ? ma : mb;          // nonneg floats: uint max ok
        int e  = (int)((mx >> 23) & 0xFF);        // biased exponent of wave max
        int Me = 284 - e;                         // mult exp: max -> ~2^30
        Me = Me < 1 ? 1 : (Me > 254 ? 254 : Me);
        float M = __builtin_bit_cast(float, Me << 23);
        S2  += Me - 127;
        prev *= M;
        dgp  *= M;
    }
#pragma unroll
    for (int k = 0; k < TAIL; ++k) {
        float xv   = xs[xb + k];
        float df   = xv - p;
        float w    = exp2_fast(-(df * df));
        w          = (t <= range) ? w : 0.0f;
        float left = wave_shr1(prev);
        float sum  = (prev + left) + dgp;
        dgp  = left;
        prev = sum * w;
        ++t;
    }

    // lane 63 holds Z for cell (511, 63):  D = (S2 - log2 Z) * ln2
    if (lane == 63) {
        float D = ((float)S2 - log2f(prev)) * LN2;
        out[b * NFILT + f] = D * (1.0f / (float)T_LEN);
    }
}

extern "C" void kernel_launch(void* const* d_in, const int* in_sizes, int n_in,
                              void* d_out, int out_size, void* d_ws, size_t ws_size,
                              hipStream_t stream) {
    const float* x      = (const float*)d_in[0];
    const float* protos = (const float*)d_in[1];
    float* out          = (float*)d_out;

    dim3 grid(NBATCH * (NFILT / 4));  // 512 blocks: 8 f-groups per batch row
    dim3 block(256);                  // 4 waves, one (b,f) problem each
    hipLaunchKernelGGL(dtw_kernel, grid, block, 0, stream, x, protos, out);
}

// Round 3
// 31.139 us; speedup vs baseline: 3.3557x; 1.0664x over previous
//
#include <hip/hip_runtime.h>

#define T_LEN  512
#define K_LEN  64
#define NFILT  32
#define NBATCH 64
#define XOFS   64                // pad: min element index = XOFS-63 >= 0
#define XS_SZ  640               // max element index read = 639
#define CHUNK  32
#define SQRT_LOG2E 1.2011224087864498f
#define LN2        0.6931471805599453f

// result[lane] = src[lane-1], lane0 -> 0 (DPP wave_shr:1, bound_ctrl=1)
static __device__ __forceinline__ float wave_shr1(float x) {
    int r = __builtin_amdgcn_update_dpp(0, __builtin_bit_cast(int, x),
                                        0x138, 0xF, 0xF, true);
    return __builtin_bit_cast(float, r);
}

template <int N>
static __device__ __forceinline__ float row_ror(float x) {
    int r = __builtin_amdgcn_update_dpp(0, __builtin_bit_cast(int, x),
                                        0x120 + N, 0xF, 0xF, true);
    return __builtin_bit_cast(float, r);
}

static __device__ __forceinline__ float exp2_fast(float x) {
#if __has_builtin(__builtin_amdgcn_exp2f)
    return __builtin_amdgcn_exp2f(x);
#else
    return exp2f(x);
#endif
}

// Linear-domain band-limited soft-DTW. One wave per (b,f); lane j = column j.
// Z = 2^S2 * exp(-D);  Z[i,j] = exp(-C[i,j]) * (Z[i-1,j] + Z[i,j-1] + Z[i-1,j-1])
// x-stream register-double-buffered per 32-step chunk to keep ds_read latency
// off the recurrence chain; wave-uniform power-of-2 renorm once per chunk.
__global__ __launch_bounds__(256) void dtw_kernel(const float* __restrict__ x,
                                                  const float* __restrict__ protos,
                                                  float* __restrict__ out) {
    __shared__ float xs[XS_SZ];
    const int tid  = threadIdx.x;
    const int lane = tid & 63;
    const int wid  = tid >> 6;
    const int b    = blockIdx.x >> 3;
    const int f    = ((blockIdx.x & 7) << 2) | wid;

    for (int t0 = tid; t0 < XS_SZ; t0 += 256) {
        int i = t0 - XOFS;
        xs[t0] = (i >= 0 && i < T_LEN) ? x[b * T_LEN + i] * SQRT_LOG2E : 0.0f;
    }
    __syncthreads();

    const float p  = protos[f * K_LEN + lane] * SQRT_LOG2E;
    const float jj = (float)lane / 63.0f;

    // exact fp32 band interval per column (same predicate as reference)
    int a0 = 0, b0 = T_LEN - 1;
    while (a0 < b0) { int m = (a0 + b0) >> 1;
        if ((float)m / 511.0f - jj >= -0.2f) b0 = m; else a0 = m + 1; }
    const int ilo = a0;
    a0 = 0; b0 = T_LEN - 1;
    while (a0 < b0) { int m = (a0 + b0 + 1) >> 1;
        if ((float)m / 511.0f - jj <= 0.2f) a0 = m; else b0 = m - 1; }
    const int ihi = a0;

    const unsigned range = (unsigned)(ihi - ilo);
    unsigned t = (unsigned)(-(lane + ilo));     // t = d - (lane+ilo)
    float prev = 0.0f;
    float dgp  = (lane == 0) ? 1.0f : 0.0f;     // Z[-1,-1] = 1
    int   S2   = 0;
    int   base = XOFS - lane;                   // element index at d = 0

    float A[CHUNK], B[CHUNK];
#pragma unroll
    for (int k = 0; k < CHUNK; ++k) A[k] = xs[base + k];

#define STEP(XV) do {                                   \
        float df_   = (XV) - p;                         \
        float w_    = exp2_fast(-(df_ * df_));          \
        w_          = (t <= range) ? w_ : 0.0f;         \
        float a_    = prev + dgp;      /* off-chain */  \
        float left_ = wave_shr1(prev);                  \
        dgp  = left_;                                   \
        prev = (a_ + left_) * w_;                       \
        ++t;                                            \
    } while (0)

#define RENORM() do {                                                        \
        float m_ = prev;                                                     \
        m_ = fmaxf(m_, row_ror<8>(m_));                                      \
        m_ = fmaxf(m_, row_ror<4>(m_));                                      \
        m_ = fmaxf(m_, row_ror<2>(m_));                                      \
        m_ = fmaxf(m_, row_ror<1>(m_));                                      \
        int mi_ = __builtin_bit_cast(int, m_);                               \
        unsigned r0_ = (unsigned)__builtin_amdgcn_readlane(mi_, 0);          \
        unsigned r1_ = (unsigned)__builtin_amdgcn_readlane(mi_, 16);         \
        unsigned r2_ = (unsigned)__builtin_amdgcn_readlane(mi_, 32);         \
        unsigned r3_ = (unsigned)__builtin_amdgcn_readlane(mi_, 48);         \
        unsigned ra_ = r0_ > r1_ ? r0_ : r1_;                                \
        unsigned rb_ = r2_ > r3_ ? r2_ : r3_;                                \
        unsigned mx_ = ra_ > rb_ ? ra_ : rb_;                                \
        int e_  = (int)((mx_ >> 23) & 0xFF);                                 \
        int Me_ = 284 - e_;                                                  \
        Me_ = Me_ < 1 ? 1 : (Me_ > 254 ? 254 : Me_);                         \
        float M_ = __builtin_bit_cast(float, Me_ << 23);                     \
        S2  += Me_ - 127;                                                    \
        prev *= M_;                                                          \
        dgp  *= M_;                                                          \
    } while (0)

#pragma unroll 1
    for (int cc = 0; cc < 8; ++cc) {
        // chunk 2cc with A; prefetch chunk 2cc+1 into B
#pragma unroll
        for (int k = 0; k < CHUNK; ++k) B[k] = xs[base + CHUNK + k];
#pragma unroll
        for (int k = 0; k < CHUNK; ++k) STEP(A[k]);
        RENORM();
        base += CHUNK;
        // chunk 2cc+1 with B; prefetch chunk 2cc+2 into A
#pragma unroll
        for (int k = 0; k < CHUNK; ++k) A[k] = xs[base + CHUNK + k];
#pragma unroll
        for (int k = 0; k < CHUNK; ++k) STEP(B[k]);
        RENORM();
        base += CHUNK;
    }
    // chunk 16 (steps 512..543) with A; prefetch tail into B
#pragma unroll
    for (int k = 0; k < CHUNK; ++k) B[k] = xs[base + CHUNK + k];
#pragma unroll
    for (int k = 0; k < CHUNK; ++k) STEP(A[k]);
    RENORM();
    // tail: steps 544..574 (31 steps) with B
#pragma unroll
    for (int k = 0; k < 31; ++k) STEP(B[k]);

    if (lane == 63) {
        float D = ((float)S2 - log2f(prev)) * LN2;
        out[b * NFILT + f] = D * (1.0f / (float)T_LEN);
    }
#undef STEP
#undef RENORM
}

extern "C" void kernel_launch(void* const* d_in, const int* in_sizes, int n_in,
                              void* d_out, int out_size, void* d_ws, size_t ws_size,
                              hipStream_t stream) {
    const float* x      = (const float*)d_in[0];
    const float* protos = (const float*)d_in[1];
    float* out          = (float*)d_out;

    dim3 grid(NBATCH * (NFILT / 4));
    dim3 block(256);
    hipLaunchKernelGGL(dtw_kernel, grid, block, 0, stream, x, protos, out);
}

// Round 4
// 29.818 us; speedup vs baseline: 3.5044x; 1.0443x over previous
//
#include <hip/hip_runtime.h>

#define T_LEN  512
#define K_LEN  64
#define NFILT  32
#define NBATCH 64
#define XOFS   64                // pad: min element index = XOFS-63 >= 1
#define XS_SZ  640               // max element index read = 639
#define CHUNK  32
#define SQRT_LOG2E 1.2011224087864498f
#define LN2        0.6931471805599453f

// result[lane] = src[lane-1], lane0 -> 0 (DPP wave_shr:1, bound_ctrl=1)
static __device__ __forceinline__ float wave_shr1(float x) {
    int r = __builtin_amdgcn_update_dpp(0, __builtin_bit_cast(int, x),
                                        0x138, 0xF, 0xF, true);
    return __builtin_bit_cast(float, r);
}

template <int N>
static __device__ __forceinline__ float row_ror(float x) {
    int r = __builtin_amdgcn_update_dpp(0, __builtin_bit_cast(int, x),
                                        0x120 + N, 0xF, 0xF, true);
    return __builtin_bit_cast(float, r);
}

static __device__ __forceinline__ float exp2_fast(float x) {
#if __has_builtin(__builtin_amdgcn_exp2f)
    return __builtin_amdgcn_exp2f(x);
#else
    return exp2f(x);
#endif
}

// Linear-domain band-limited soft-DTW, TWO problems per wave (f and f+16,
// same b -> shared x-stream, shared band/loop control, two independent
// recurrence chains for ILP). Z = 2^S2 * exp(-D);
// Z[i,j] = exp(-C[i,j]) * (Z[i-1,j] + Z[i,j-1] + Z[i-1,j-1]).
__global__ __launch_bounds__(256) void dtw_kernel(const float* __restrict__ x,
                                                  const float* __restrict__ protos,
                                                  float* __restrict__ out) {
    __shared__ float xs[XS_SZ];
    const int tid  = threadIdx.x;
    const int lane = tid & 63;
    const int wid  = tid >> 6;
    const int b    = blockIdx.x >> 2;               // 256 blocks: 4 per b
    const int fA   = ((blockIdx.x & 3) << 2) | wid; // 0..15
    const int fB   = fA + 16;

    for (int t0 = tid; t0 < XS_SZ; t0 += 256) {
        int i = t0 - XOFS;
        xs[t0] = (i >= 0 && i < T_LEN) ? x[b * T_LEN + i] * SQRT_LOG2E : 0.0f;
    }
    __syncthreads();

    const float pA = protos[fA * K_LEN + lane] * SQRT_LOG2E;
    const float pB = protos[fB * K_LEN + lane] * SQRT_LOG2E;
    const float jj = (float)lane / 63.0f;

    // exact fp32 band interval per column (same predicate as reference)
    int a0 = 0, b0 = T_LEN - 1;
    while (a0 < b0) { int m = (a0 + b0) >> 1;
        if ((float)m / 511.0f - jj >= -0.2f) b0 = m; else a0 = m + 1; }
    const int ilo = a0;
    a0 = 0; b0 = T_LEN - 1;
    while (a0 < b0) { int m = (a0 + b0 + 1) >> 1;
        if ((float)m / 511.0f - jj <= 0.2f) a0 = m; else b0 = m - 1; }
    const int ihi = a0;

    const unsigned range = (unsigned)(ihi - ilo);
    unsigned t = (unsigned)(-(lane + ilo));
    float prevA = 0.0f, prevB = 0.0f;
    float dgpA  = (lane == 0) ? 1.0f : 0.0f;
    float dgpB  = dgpA;
    int   S2A = 0, S2B = 0;
    int   base = XOFS - lane;

    float A[CHUNK], B[CHUNK];
#pragma unroll
    for (int k = 0; k < CHUNK; ++k) A[k] = xs[base + k];

#define STEP(XV) do {                                     \
        float xv_  = (XV);                                \
        float dfA_ = xv_ - pA;                            \
        float dfB_ = xv_ - pB;                            \
        float wA_  = exp2_fast(-(dfA_ * dfA_));           \
        float wB_  = exp2_fast(-(dfB_ * dfB_));           \
        bool  in_  = (t <= range);                        \
        wA_ = in_ ? wA_ : 0.0f;                           \
        wB_ = in_ ? wB_ : 0.0f;                           \
        float aA_ = prevA + dgpA;                         \
        float aB_ = prevB + dgpB;                         \
        float lA_ = wave_shr1(prevA);                     \
        float lB_ = wave_shr1(prevB);                     \
        dgpA = lA_; dgpB = lB_;                           \
        prevA = (aA_ + lA_) * wA_;                        \
        prevB = (aB_ + lB_) * wB_;                        \
        ++t;                                              \
    } while (0)

#define RENORM_HALF(PV, DG, S2) do {                                         \
        float m_ = PV;                                                       \
        m_ = fmaxf(m_, row_ror<8>(m_));                                      \
        m_ = fmaxf(m_, row_ror<4>(m_));                                      \
        m_ = fmaxf(m_, row_ror<2>(m_));                                      \
        m_ = fmaxf(m_, row_ror<1>(m_));                                      \
        int mi_ = __builtin_bit_cast(int, m_);                               \
        unsigned r0_ = (unsigned)__builtin_amdgcn_readlane(mi_, 0);          \
        unsigned r1_ = (unsigned)__builtin_amdgcn_readlane(mi_, 16);         \
        unsigned r2_ = (unsigned)__builtin_amdgcn_readlane(mi_, 32);         \
        unsigned r3_ = (unsigned)__builtin_amdgcn_readlane(mi_, 48);         \
        unsigned ra_ = r0_ > r1_ ? r0_ : r1_;                                \
        unsigned rb_ = r2_ > r3_ ? r2_ : r3_;                                \
        unsigned mx_ = ra_ > rb_ ? ra_ : rb_;                                \
        int e_  = (int)((mx_ >> 23) & 0xFF);                                 \
        int Me_ = 284 - e_;                                                  \
        Me_ = Me_ < 1 ? 1 : (Me_ > 254 ? 254 : Me_);                         \
        float M_ = __builtin_bit_cast(float, Me_ << 23);                     \
        S2 += Me_ - 127;                                                     \
        PV *= M_;                                                            \
        DG *= M_;                                                            \
    } while (0)

#define RENORM() do { RENORM_HALF(prevA, dgpA, S2A);                         \
                      RENORM_HALF(prevB, dgpB, S2B); } while (0)

#pragma unroll 1
    for (int cc = 0; cc < 8; ++cc) {
#pragma unroll
        for (int k = 0; k < CHUNK; ++k) B[k] = xs[base + CHUNK + k];
#pragma unroll
        for (int k = 0; k < CHUNK; ++k) STEP(A[k]);
        RENORM();
        base += CHUNK;
#pragma unroll
        for (int k = 0; k < CHUNK; ++k) A[k] = xs[base + CHUNK + k];
#pragma unroll
        for (int k = 0; k < CHUNK; ++k) STEP(B[k]);
        RENORM();
        base += CHUNK;
    }
    // steps 512..543 with A; prefetch tail into B
#pragma unroll
    for (int k = 0; k < CHUNK; ++k) B[k] = xs[base + CHUNK + k];
#pragma unroll
    for (int k = 0; k < CHUNK; ++k) STEP(A[k]);
    RENORM();
    // tail: steps 544..574 (31 steps)
#pragma unroll
    for (int k = 0; k < 31; ++k) STEP(B[k]);

    if (lane == 63) {
        float DA = ((float)S2A - log2f(prevA)) * LN2;
        float DB = ((float)S2B - log2f(prevB)) * LN2;
        out[b * NFILT + fA] = DA * (1.0f / (float)T_LEN);
        out[b * NFILT + fB] = DB * (1.0f / (float)T_LEN);
    }
#undef STEP
#undef RENORM_HALF
#undef RENORM
}

extern "C" void kernel_launch(void* const* d_in, const int* in_sizes, int n_in,
                              void* d_out, int out_size, void* d_ws, size_t ws_size,
                              hipStream_t stream) {
    const float* x      = (const float*)d_in[0];
    const float* protos = (const float*)d_in[1];
    float* out          = (float*)d_out;

    dim3 grid(NBATCH * 4);   // 256 blocks, 1 per CU; 4 waves = 1/SIMD
    dim3 block(256);         // each wave: 2 problems (f, f+16), same b
    hipLaunchKernelGGL(dtw_kernel, grid, block, 0, stream, x, protos, out);
}

// Round 5
// 28.006 us; speedup vs baseline: 3.7312x; 1.0647x over previous
//
#include <hip/hip_runtime.h>

#define T_LEN  512
#define K_LEN  64
#define NFILT  32
#define NBATCH 64
#define XOFS   64                // pad: min element index = XOFS-63 >= 1
#define XS_SZ  640               // max element index read = 639
#define CHUNK  32
#define SQRT_LOG2E 1.2011224087864498f
#define LN2        0.6931471805599453f

// result[lane] = src[lane-1], lane0 -> 0 (DPP wave_shr:1, bound_ctrl=1)
static __device__ __forceinline__ float wave_shr1(float x) {
    int r = __builtin_amdgcn_update_dpp(0, __builtin_bit_cast(int, x),
                                        0x138, 0xF, 0xF, true);
    return __builtin_bit_cast(float, r);
}

template <int N>
static __device__ __forceinline__ float row_ror(float x) {
    int r = __builtin_amdgcn_update_dpp(0, __builtin_bit_cast(int, x),
                                        0x120 + N, 0xF, 0xF, true);
    return __builtin_bit_cast(float, r);
}

static __device__ __forceinline__ float exp2_fast(float x) {
#if __has_builtin(__builtin_amdgcn_exp2f)
    return __builtin_amdgcn_exp2f(x);
#else
    return exp2f(x);
#endif
}

// Linear-domain band-limited soft-DTW, TWO problems per wave (f, f+16; same b).
// Z = 2^S2 * exp(-D);  Z[i,j] = exp(-C[i,j]) * (Z[i-1,j] + Z[i,j-1] + Z[i-1,j-1])
// x-stream register-double-buffered per 32-step chunk; sched_barrier(0) pins
// the prefetch loads a full chunk ahead of use (the backend otherwise sinks
// them next to their uses -- round 4 ran at VGPR=40, proving the arrays were
// dissolved and ds_read latency sat on the recurrence chain).
__global__ __launch_bounds__(256) void dtw_kernel(const float* __restrict__ x,
                                                  const float* __restrict__ protos,
                                                  float* __restrict__ out) {
    __shared__ float xs[XS_SZ];
    const int tid  = threadIdx.x;
    const int lane = tid & 63;
    const int wid  = tid >> 6;
    const int b    = blockIdx.x >> 2;               // 256 blocks: 4 per b
    const int fA   = ((blockIdx.x & 3) << 2) | wid; // 0..15
    const int fB   = fA + 16;

    for (int t0 = tid; t0 < XS_SZ; t0 += 256) {
        int i = t0 - XOFS;
        xs[t0] = (i >= 0 && i < T_LEN) ? x[b * T_LEN + i] * SQRT_LOG2E : 0.0f;
    }
    __syncthreads();

    const float pA = protos[fA * K_LEN + lane] * SQRT_LOG2E;
    const float pB = protos[fB * K_LEN + lane] * SQRT_LOG2E;
    const float jj = (float)lane / 63.0f;

    // exact fp32 band interval per column (same predicate as reference)
    int a0 = 0, b0 = T_LEN - 1;
    while (a0 < b0) { int m = (a0 + b0) >> 1;
        if ((float)m / 511.0f - jj >= -0.2f) b0 = m; else a0 = m + 1; }
    const int ilo = a0;
    a0 = 0; b0 = T_LEN - 1;
    while (a0 < b0) { int m = (a0 + b0 + 1) >> 1;
        if ((float)m / 511.0f - jj <= 0.2f) a0 = m; else b0 = m - 1; }
    const int ihi = a0;

    const unsigned range = (unsigned)(ihi - ilo);
    unsigned t = (unsigned)(-(lane + ilo));
    float prevA = 0.0f, prevB = 0.0f;
    float dgpA  = (lane == 0) ? 1.0f : 0.0f;
    float dgpB  = dgpA;
    int   S2A = 0, S2B = 0;
    int   base = XOFS - lane;

    float A[CHUNK], Bv[CHUNK];
#pragma unroll
    for (int k = 0; k < CHUNK; ++k) A[k] = xs[base + k];
    __builtin_amdgcn_sched_barrier(0);   // pin initial loads here

    // band mask folded into exp arg: out-of-band -> exp2(-3e38) == 0 exactly
#define STEP(XV) do {                                         \
        float xv_  = (XV);                                    \
        float sel_ = (t <= range) ? 0.0f : -3.0e38f;          \
        float dfA_ = xv_ - pA;                                \
        float dfB_ = xv_ - pB;                                \
        float wA_  = exp2_fast(__builtin_fmaf(dfA_, -dfA_, sel_)); \
        float wB_  = exp2_fast(__builtin_fmaf(dfB_, -dfB_, sel_)); \
        float lA_  = wave_shr1(prevA);                        \
        float lB_  = wave_shr1(prevB);                        \
        float aA_  = prevA + dgpA;                            \
        float aB_  = prevB + dgpB;                            \
        dgpA = lA_; dgpB = lB_;                               \
        prevA = (aA_ + lA_) * wA_;                            \
        prevB = (aB_ + lB_) * wB_;                            \
        ++t;                                                  \
    } while (0)

#define RENORM_HALF(PV, DG, S2) do {                                         \
        float m_ = PV;                                                       \
        m_ = fmaxf(m_, row_ror<8>(m_));                                      \
        m_ = fmaxf(m_, row_ror<4>(m_));                                      \
        m_ = fmaxf(m_, row_ror<2>(m_));                                      \
        m_ = fmaxf(m_, row_ror<1>(m_));                                      \
        int mi_ = __builtin_bit_cast(int, m_);                               \
        unsigned r0_ = (unsigned)__builtin_amdgcn_readlane(mi_, 0);          \
        unsigned r1_ = (unsigned)__builtin_amdgcn_readlane(mi_, 16);         \
        unsigned r2_ = (unsigned)__builtin_amdgcn_readlane(mi_, 32);         \
        unsigned r3_ = (unsigned)__builtin_amdgcn_readlane(mi_, 48);         \
        unsigned ra_ = r0_ > r1_ ? r0_ : r1_;                                \
        unsigned rb_ = r2_ > r3_ ? r2_ : r3_;                                \
        unsigned mx_ = ra_ > rb_ ? ra_ : rb_;                                \
        int e_  = (int)((mx_ >> 23) & 0xFF);                                 \
        int Me_ = 284 - e_;                                                  \
        Me_ = Me_ < 1 ? 1 : (Me_ > 254 ? 254 : Me_);                         \
        float M_ = __builtin_bit_cast(float, Me_ << 23);                     \
        S2 += Me_ - 127;                                                     \
        PV *= M_;                                                            \
        DG *= M_;                                                            \
    } while (0)

#define RENORM() do { RENORM_HALF(prevA, dgpA, S2A);                         \
                      RENORM_HALF(prevB, dgpB, S2B); } while (0)

#pragma unroll 1
    for (int cc = 0; cc < 8; ++cc) {
        // prefetch next chunk into Bv, pinned BEFORE this chunk's compute
#pragma unroll
        for (int k = 0; k < CHUNK; ++k) Bv[k] = xs[base + CHUNK + k];
        __builtin_amdgcn_sched_barrier(0);
#pragma unroll
        for (int k = 0; k < CHUNK; ++k) STEP(A[k]);
        RENORM();
        __builtin_amdgcn_sched_barrier(0);
        base += CHUNK;
        // prefetch next chunk into A, pinned BEFORE this chunk's compute
#pragma unroll
        for (int k = 0; k < CHUNK; ++k) A[k] = xs[base + CHUNK + k];
        __builtin_amdgcn_sched_barrier(0);
#pragma unroll
        for (int k = 0; k < CHUNK; ++k) STEP(Bv[k]);
        RENORM();
        __builtin_amdgcn_sched_barrier(0);
        base += CHUNK;
    }
    // steps 512..543 with A; prefetch tail (544..574 + pad) into Bv
#pragma unroll
    for (int k = 0; k < CHUNK; ++k) Bv[k] = xs[base + CHUNK + k];
    __builtin_amdgcn_sched_barrier(0);
#pragma unroll
    for (int k = 0; k < CHUNK; ++k) STEP(A[k]);
    RENORM();
    // tail: steps 544..574 (31 steps)
#pragma unroll
    for (int k = 0; k < 31; ++k) STEP(Bv[k]);

    if (lane == 63) {
        float DA = ((float)S2A - log2f(prevA)) * LN2;
        float DB = ((float)S2B - log2f(prevB)) * LN2;
        out[b * NFILT + fA] = DA * (1.0f / (float)T_LEN);
        out[b * NFILT + fB] = DB * (1.0f / (float)T_LEN);
    }
#undef STEP
#undef RENORM_HALF
#undef RENORM
}

extern "C" void kernel_launch(void* const* d_in, const int* in_sizes, int n_in,
                              void* d_out, int out_size, void* d_ws, size_t ws_size,
                              hipStream_t stream) {
    const float* x      = (const float*)d_in[0];
    const float* protos = (const float*)d_in[1];
    float* out          = (float*)d_out;

    dim3 grid(NBATCH * 4);   // 256 blocks; 4 waves/block = 1 wave/SIMD
    dim3 block(256);         // each wave: 2 problems (f, f+16), same b
    hipLaunchKernelGGL(dtw_kernel, grid, block, 0, stream, x, protos, out);
}